// Round 18
// baseline (186.490 us; speedup 1.0000x reference)
//
#include <hip/hip_runtime.h>
#include <hip/hip_bf16.h>
#include <math.h>

// ---------------------------------------------------------------------------
// LDSTNet forward. B=64, C=64, T=64, N=25, Ci=32. Pools: R1=19, R2=15.
//
// Workspace layout (floats):
//   (free)  @ 0          : 6,553,600
//   R1      @ 6,553,600  : 6,553,600  Pp2 bf16 [b][t][1600] -> ZH/HbTB bf16 [col][128]
//   R2      @ 13,107,200 : 6,553,600  HbT_A bf16 [b][1600][128] (0..63=x, 64..127=out1)
//   logits  @ 19,660,800 : 54,400     f32 [b][850] (atomic pool accumulators)
//   preb    @ 24,641,536 : 4,980,736  Wb | WgT | sconst | ubuf2 | ubuf3
//   F19     @ 29,622,272 : 30,400
//   F15     @ 29,652,672 : 24,000
//   uvbuf   @ 29,676,672 : 320
// ---------------------------------------------------------------------------

#define BN_SCALE_F 0.9999950000374997f

typedef __attribute__((ext_vector_type(8))) short short8;
typedef __attribute__((ext_vector_type(4))) float f32x4;

// ---- merged prep: block 0 = uv/sconst; 1..32 = WgT; 33..224 = Wb; 225..437 = zero logits
__global__ void prep_all(const float* __restrict__ Wt2, const float* __restrict__ bt2,
                         const float* __restrict__ Wph2, const float* __restrict__ bph2,
                         const float* __restrict__ wcat2,
                         const float* __restrict__ Wt3, const float* __restrict__ bt3,
                         const float* __restrict__ Wph3, const float* __restrict__ bph3,
                         const float* __restrict__ wcat3,
                         const float* __restrict__ Ck2, const float* __restrict__ Ck3,
                         const float* __restrict__ Wg2, const float* __restrict__ Wg3,
                         const float* __restrict__ Wtcn,
                         float* __restrict__ uv, float* __restrict__ sconst,
                         __hip_bfloat16* __restrict__ WgT,
                         __hip_bfloat16* __restrict__ Wb,
                         float* __restrict__ logits) {
  const int bid = blockIdx.x;
  const int tid = threadIdx.x;
  if (bid == 0) {
    int c = tid;
    if (c < 64) {
      float s1 = 0.f, s2 = 0.f, s3 = 0.f, s4 = 0.f;
      for (int i = 0; i < 32; ++i) {
        s1 += wcat2[i]      * Wt2[i * 64 + c];
        s2 += wcat2[32 + i] * Wph2[i * 64 + c];
        s3 += wcat3[i]      * Wt3[i * 64 + c];
        s4 += wcat3[32 + i] * Wph3[i * 64 + c];
      }
      uv[c] = s1; uv[64 + c] = s2; uv[128 + c] = s3; uv[192 + c] = s4;
    }
    if (c == 0) {
      float c1 = 0.f, c2 = 0.f, c3 = 0.f, c4 = 0.f;
      for (int i = 0; i < 32; ++i) {
        c1 += wcat2[i] * bt2[i];       c2 += wcat2[32 + i] * bph2[i];
        c3 += wcat3[i] * bt3[i];       c4 += wcat3[32 + i] * bph3[i];
      }
      uv[256] = c1; uv[257] = c2; uv[258] = c3; uv[259] = c4;
    }
    if (c >= 64 && c < 89) {
      int n = c - 64;
      float s2 = 1.f, s3 = 1.f;
      for (int m = 0; m < 19; ++m) s2 += Ck2[n * 19 + m];
      for (int m = 0; m < 15; ++m) s3 += Ck3[n * 15 + m];
      sconst[n] = s2; sconst[25 + n] = s3;
    }
  } else if (bid < 33) {
    int idx = (bid - 1) * 256 + tid;
    int g = idx >> 6, c = idx & 63;
    float v = (g < 64) ? Wg2[g * 64 + c] : Wg3[(g - 64) * 64 + c];
    WgT[idx] = __float2bfloat16(v);
  } else if (bid < 225) {
    int idx = (bid - 33) * 256 + tid;
    int ci = idx & 255;
    int rest = idx >> 8;
    int o = rest & 63, kt = rest >> 6;
    Wb[idx] = __float2bfloat16(Wtcn[(o * 256 + ci) * 3 + kt]);
  } else {
    int idx = (bid - 225) * 256 + tid;
    if (idx < 54400) logits[idx] = 0.f;
  }
}

// ---- ldnet1 via MFMA: one wave per (b,t), 4 waves/block, NO BARRIERS.
__global__ __launch_bounds__(256, 4) void ldnet1_mfma(
    const float* __restrict__ x, const float* __restrict__ A,
    const float* __restrict__ uvg,
    __hip_bfloat16* __restrict__ Pp2,
    __hip_bfloat16* __restrict__ HbTA,
    float* __restrict__ ubuf2, float* __restrict__ ubuf3) {
  const int b = blockIdx.x >> 4;
  const int t0 = (blockIdx.x & 15) << 2;
  const int tid = threadIdx.x;
  const int w = tid >> 6;
  const int l = tid & 63;
  const int t = t0 + w;
  const int lr = l & 15, lg = l >> 4;

  __shared__ __hip_bfloat16 XbS[4][64 * 40];   // x-tile -> otb -> P; cols 25..31 zero
  __shared__ __hip_bfloat16 FTS[4][32 * 40];   // FT[m][n] = FA[n][m]
  __shared__ float scS[4][25 * 25];            // gram scores only
  __hip_bfloat16* Xb = XbS[w];
  __hip_bfloat16* FT = FTS[w];
  float* scf = scS[w];

  const float* xp = x + b * 102400 + t * 25;   // + c*1600 + n
  typedef union { short8 v; ushort u[8]; } frag_u;

  // phase 0: zero FT; stage x-tile bf16 into Xb cols 0..31 (25..31 = 0).
  {
    uint32_t* z2 = (uint32_t*)FT;
    for (int i = l; i < 640; i += 64) z2[i] = 0u;
  }
  for (int idx = l; idx < 2048; idx += 64) {
    int c = idx >> 5, n = idx & 31;
    float v = (n < 25) ? xp[c * 1600 + n] : 0.f;
    Xb[c * 40 + n] = __float2bfloat16(v);
  }

  // phase 0b: HbTA x-part from LDS (lane = c)
  for (int n = 0; n < 25; ++n)
    HbTA[(size_t)(b * 1600 + t * 25 + n) * 128 + l] = Xb[l * 40 + n];

  // phase 1: gram frags from LDS + 8 MFMA -> scores
  frag_u yf[2][2];
  #pragma unroll
  for (int it = 0; it < 2; ++it) {
    const int n = it * 16 + lr;
    #pragma unroll
    for (int ks = 0; ks < 2; ++ks)
      #pragma unroll
      for (int j = 0; j < 8; ++j)
        yf[it][ks].u[j] = *(const ushort*)&Xb[(ks * 32 + lg * 8 + j) * 40 + n];
  }
  f32x4 accg[2][2];
  #pragma unroll
  for (int it = 0; it < 2; ++it)
    #pragma unroll
    for (int jt = 0; jt < 2; ++jt) {
      f32x4 a = (f32x4){0.f, 0.f, 0.f, 0.f};
      a = __builtin_amdgcn_mfma_f32_16x16x32_bf16(yf[it][0].v, yf[jt][0].v, a, 0, 0, 0);
      a = __builtin_amdgcn_mfma_f32_16x16x32_bf16(yf[it][1].v, yf[jt][1].v, a, 0, 0, 0);
      accg[it][jt] = a;
    }
  #pragma unroll
  for (int it = 0; it < 2; ++it)
    #pragma unroll
    for (int jt = 0; jt < 2; ++jt)
      #pragma unroll
      for (int r = 0; r < 4; ++r) {
        int i = it * 16 + lg * 4 + r;
        int j = jt * 16 + lr;
        if (i < 25 && j < 25) scf[i * 25 + j] = accg[it][jt][r];
      }

  // phase 2: softmax rows (lanes 0..24) -> FT[m*40+n] = FA[n][m]
  if (l < 25) {
    const int n = l;
    float f[25];
    float mx = -1e30f;
    #pragma unroll
    for (int m = 0; m < 25; ++m) { f[m] = scf[n * 25 + m] * 0.125f; mx = fmaxf(mx, f[m]); }
    float sum = 0.f;
    #pragma unroll
    for (int m = 0; m < 25; ++m) { f[m] = __expf(f[m] - mx); sum += f[m]; }
    float inv = 1.f / sum;
    #pragma unroll
    for (int m = 0; m < 25; ++m) {
      float v = f[m] * inv + A[n * 25 + m];
      FT[m * 40 + n] = __float2bfloat16(v);
    }
  }

  // phase 3: Q = out1^T. A = FT rows m, B = X rows c (short8 from LDS).
  short8 fa_[2];
  fa_[0] = *(const short8*)(&FT[lr * 40 + lg * 8]);
  fa_[1] = *(const short8*)(&FT[(16 + lr) * 40 + lg * 8]);
  short8 xb2v[4];
  #pragma unroll
  for (int jt = 0; jt < 4; ++jt)
    xb2v[jt] = *(const short8*)(&Xb[(jt * 16 + lr) * 40 + lg * 8]);
  f32x4 q_[2][4];
  #pragma unroll
  for (int it = 0; it < 2; ++it)
    #pragma unroll
    for (int jt = 0; jt < 4; ++jt) {
      f32x4 a = (f32x4){0.f, 0.f, 0.f, 0.f};
      q_[it][jt] = __builtin_amdgcn_mfma_f32_16x16x32_bf16(fa_[it], xb2v[jt], a, 0, 0, 0);
    }
  #pragma unroll
  for (int it = 0; it < 2; ++it)
    #pragma unroll
    for (int jt = 0; jt < 4; ++jt)
      #pragma unroll
      for (int r = 0; r < 4; ++r) {
        int m = it * 16 + lg * 4 + r;
        int c = jt * 16 + lr;
        if (m < 25) {
          __hip_bfloat16 h = __float2bfloat16(q_[it][jt][r]);
          Xb[c * 40 + m] = h;
          HbTA[(size_t)(b * 1600 + t * 25 + m) * 128 + 64 + c] = h;
        }
      }

  // phase 4: uu2/uu3 from otb (lanes 0..24)
  if (l < 25) {
    float s2 = uvg[256], s3 = uvg[258];
    #pragma unroll 8
    for (int c = 0; c < 64; ++c) {
      float o = __bfloat162float(Xb[c * 40 + l]);
      s2 += uvg[c] * o;
      s3 += uvg[128 + c] * o;
    }
    ubuf2[b * 1600 + t * 25 + l] = s2;
    ubuf3[b * 1600 + t * 25 + l] = s3;
  }

  // phase 5: P = otb @ FA
  short8 ofr[4];
  #pragma unroll
  for (int it = 0; it < 4; ++it)
    ofr[it] = *(const short8*)(&Xb[(it * 16 + lr) * 40 + lg * 8]);
  f32x4 p_[4][2];
  #pragma unroll
  for (int it = 0; it < 4; ++it)
    #pragma unroll
    for (int jt = 0; jt < 2; ++jt) {
      f32x4 a = (f32x4){0.f, 0.f, 0.f, 0.f};
      p_[it][jt] = __builtin_amdgcn_mfma_f32_16x16x32_bf16(ofr[it], fa_[jt], a, 0, 0, 0);
    }
  #pragma unroll
  for (int it = 0; it < 4; ++it)
    #pragma unroll
    for (int jt = 0; jt < 2; ++jt)
      #pragma unroll
      for (int r = 0; r < 4; ++r) {
        int c = it * 16 + lg * 4 + r;
        int n = jt * 16 + lr;
        if (n < 25) Xb[c * 40 + n] = __float2bfloat16(p_[it][jt][r]);
      }

  // phase 6: Pp2 bf16 coalesced
  for (int idx = l; idx < 1600; idx += 64) {
    int c = idx / 25, n = idx - c * 25;
    Pp2[b * 102400 + t * 1600 + idx] = Xb[c * 40 + n];
  }
}

// ---- pool partials, block = (b, c-channel); atomicAdd into logits[b][850]
__global__ void pool_partial(const __hip_bfloat16* __restrict__ Pp2,
                             const float* __restrict__ Wp1, const float* __restrict__ Wp2,
                             const float* __restrict__ ap1_, const float* __restrict__ ap2_,
                             float* __restrict__ logits) {
  const int b = blockIdx.x >> 6;
  const int c = blockIdx.x & 63;
  const int tid = threadIdx.x;
  const float a1 = ap1_[0], a2 = ap2_[0];
  __shared__ float pg1[1600];
  __shared__ float pg2[1600];
  __shared__ float wct[64][36];
  for (int idx = tid; idx < 1600; idx += 256) {
    int t = idx / 25, n = idx - t * 25;
    float v = __bfloat162float(Pp2[b * 102400 + t * 1600 + c * 25 + n]);
    pg1[idx] = v >= 0.f ? v : a1 * v;
    pg2[idx] = v >= 0.f ? v : a2 * v;
  }
  for (int idx = tid; idx < 19 * 64; idx += 256) {
    int kl = idx & 63, r = idx >> 6;
    wct[kl][r] = Wp1[r * 4096 + (c << 6) + kl];
  }
  for (int idx = tid; idx < 15 * 64; idx += 256) {
    int kl = idx & 63, r = idx >> 6;
    wct[kl][20 + r] = Wp2[r * 4096 + (c << 6) + kl];
  }
  __syncthreads();
  if (tid < 225) {
    const int j = tid / 9;
    const int g = tid - j * 9;
    const bool br1 = (g < 5);
    const int r0 = br1 ? g * 4 : 20 + (g - 5) * 4;
    const float* pgc = br1 ? pg1 : pg2;
    float acc0 = 0.f, acc1 = 0.f, acc2 = 0.f, acc3 = 0.f;
    #pragma unroll 4
    for (int kl = 0; kl < 64; ++kl) {
      int off = kl * 25 + j;
      float p = pgc[(off & 63) * 25 + (off >> 6)];
      const float4 wv = *(const float4*)&wct[kl][r0];
      acc0 += p * wv.x; acc1 += p * wv.y; acc2 += p * wv.z; acc3 += p * wv.w;
    }
    float* lg = logits + b * 850;
    if (br1) {
      const int m = j * 19 + r0;
      atomicAdd(&lg[m], acc0); atomicAdd(&lg[m + 1], acc1); atomicAdd(&lg[m + 2], acc2);
      if (g != 4) atomicAdd(&lg[m + 3], acc3);
    } else {
      const int m = 475 + j * 15 + (r0 - 20);
      atomicAdd(&lg[m], acc0); atomicAdd(&lg[m + 1], acc1); atomicAdd(&lg[m + 2], acc2);
      if (g != 8) atomicAdd(&lg[m + 3], acc3);
    }
  }
}

// ---- per-branch softmax directly from logits (L2-hot)
__global__ void pool_reduce(const float* __restrict__ logits,
                            float* __restrict__ F19, float* __restrict__ F15) {
  const int b = blockIdx.x;
  const int tid = threadIdx.x;
  const float* lg = logits + b * 850;
  if (tid < 25) {
    const float* row = lg + tid * 19;
    float mx = -1e30f;
    for (int r = 0; r < 19; ++r) mx = fmaxf(mx, row[r]);
    float sum = 0.f;
    for (int r = 0; r < 19; ++r) sum += __expf(row[r] - mx);
    float inv = 1.f / sum;
    for (int r = 0; r < 19; ++r)
      F19[(b * 25 + tid) * 19 + r] = __expf(row[r] - mx) * inv;
  } else if (tid >= 32 && tid < 57) {
    const int j = tid - 32;
    const float* row = lg + 475 + j * 15;
    float mx = -1e30f;
    for (int r = 0; r < 15; ++r) mx = fmaxf(mx, row[r]);
    float sum = 0.f;
    for (int r = 0; r < 15; ++r) sum += __expf(row[r] - mx);
    float inv = 1.f / sum;
    for (int r = 0; r < 15; ++r)
      F15[(b * 25 + j) * 15 + r] = __expf(row[r] - mx) * inv;
  }
}

// ---- fused x2 + ldnet + attention + Z body (one wave per (b,t), NO BARRIERS).
// scf overlays FB (FB's last read precedes first scf write; wave-private, in-order DS).
template<int M>
__device__ __forceinline__ void restore_body(
    int bid, const __hip_bfloat16* __restrict__ HbTA, const float* __restrict__ F3g,
    const float* __restrict__ A,
    const float* __restrict__ uub, const float* __restrict__ wv,
    const float* __restrict__ cuv, const float* __restrict__ Ck,
    __hip_bfloat16* __restrict__ ZH, int cioff,
    __hip_bfloat16* Xb, __hip_bfloat16* FB, __hip_bfloat16* FT,
    __hip_bfloat16* AT, float* vv) {
  const int b = bid >> 4;
  const int t0 = (bid & 15) << 2;
  const int tid = threadIdx.x;
  const int w = tid >> 6;
  const int l = tid & 63;
  const int t = t0 + w;
  const int lr = l & 15, lg = l >> 4;
  float* scf = (float*)FB;   // overlay: FB read (phase 1 regs) precedes scf write (phase 2)

  typedef union { short8 v; ushort u[8]; } frag_u;
  const ushort* Hu = (const ushort*)HbTA;

  // phase 0: zero FB/FT/AT (B-operand pads must be 0)
  {
    uint32_t* z1 = (uint32_t*)FB;
    uint32_t* z2 = (uint32_t*)FT;
    uint32_t* z3 = (uint32_t*)AT;
    for (int i = l; i < 640; i += 64) { z1[i] = 0u; z2[i] = 0u; z3[i] = 0u; }
  }
  // phase 0a: FB[r*40+n] = bf16(F3[b][n][r])
  for (int idx = l; idx < M * 25; idx += 64) {
    int r = idx / 25, n = idx - r * 25;
    FB[r * 40 + n] = __float2bfloat16(F3g[(b * 25 + n) * M + r]);
  }

  // phase 1: X2 = out1 @ F3. A-frags from global HbTA (gated), B from FB.
  frag_u af0[4];
  #pragma unroll
  for (int it = 0; it < 4; ++it) {
    const int c = it * 16 + lr;
    #pragma unroll
    for (int jj = 0; jj < 8; ++jj) {
      int n = lg * 8 + jj;
      af0[it].u[jj] = (n < 25)
          ? Hu[(size_t)(b * 1600 + t * 25 + n) * 128 + 64 + c] : (ushort)0;
    }
  }
  short8 bf0[2];
  bf0[0] = *(const short8*)(&FB[lr * 40 + lg * 8]);
  bf0[1] = *(const short8*)(&FB[(16 + lr) * 40 + lg * 8]);
  f32x4 x2a[4][2];
  #pragma unroll
  for (int it = 0; it < 4; ++it)
    #pragma unroll
    for (int jt = 0; jt < 2; ++jt) {
      f32x4 a = (f32x4){0.f, 0.f, 0.f, 0.f};
      x2a[it][jt] = __builtin_amdgcn_mfma_f32_16x16x32_bf16(af0[it].v, bf0[jt], a, 0, 0, 0);
    }
  #pragma unroll
  for (int it = 0; it < 4; ++it)
    #pragma unroll
    for (int jt = 0; jt < 2; ++jt)
      #pragma unroll
      for (int rr = 0; rr < 4; ++rr) {
        int c = it * 16 + lg * 4 + rr;
        int r = jt * 16 + lr;
        float v = (r < M) ? x2a[it][jt][rr] : 0.f;
        Xb[c * 40 + r] = __float2bfloat16(v);
      }

  // phase 2: gram(X2) frags from LDS + 8 MFMA -> scores scf[i*26+j]
  frag_u yf[2][2];
  #pragma unroll
  for (int it = 0; it < 2; ++it) {
    const int n = it * 16 + lr;
    #pragma unroll
    for (int ks = 0; ks < 2; ++ks)
      #pragma unroll
      for (int j = 0; j < 8; ++j)
        yf[it][ks].u[j] = *(const ushort*)&Xb[(ks * 32 + lg * 8 + j) * 40 + n];
  }
  f32x4 accg[2][2];
  #pragma unroll
  for (int it = 0; it < 2; ++it)
    #pragma unroll
    for (int jt = 0; jt < 2; ++jt) {
      f32x4 a = (f32x4){0.f, 0.f, 0.f, 0.f};
      a = __builtin_amdgcn_mfma_f32_16x16x32_bf16(yf[it][0].v, yf[jt][0].v, a, 0, 0, 0);
      a = __builtin_amdgcn_mfma_f32_16x16x32_bf16(yf[it][1].v, yf[jt][1].v, a, 0, 0, 0);
      accg[it][jt] = a;
    }
  #pragma unroll
  for (int it = 0; it < 2; ++it)
    #pragma unroll
    for (int jt = 0; jt < 2; ++jt)
      #pragma unroll
      for (int r = 0; r < 4; ++r) {
        int i = it * 16 + lg * 4 + r;
        int j = jt * 16 + lr;
        if (i < M && j < M) scf[i * 26 + j] = accg[it][jt][r];
      }

  // phase 3: softmax rows (lanes 0..M-1) -> FT[m*40+n]
  if (l < M) {
    const int n = l;
    float f[M];
    float mx = -1e30f;
    #pragma unroll
    for (int m = 0; m < M; ++m) { f[m] = scf[n * 26 + m] * 0.125f; mx = fmaxf(mx, f[m]); }
    float sum = 0.f;
    #pragma unroll
    for (int m = 0; m < M; ++m) { f[m] = __expf(f[m] - mx); sum += f[m]; }
    float inv = 1.f / sum;
    #pragma unroll
    for (int m = 0; m < M; ++m) {
      float v = f[m] * inv + A[n * M + m];
      FT[m * 40 + n] = __float2bfloat16(v);
    }
  }

  // phase 4: ot = X2 @ FA (K=32), scatter into Xb (cols >= M -> 0)
  short8 xf[4], ff[2];
  #pragma unroll
  for (int it = 0; it < 4; ++it)
    xf[it] = *(const short8*)(&Xb[(it * 16 + lr) * 40 + lg * 8]);
  #pragma unroll
  for (int jt = 0; jt < 2; ++jt)
    ff[jt] = *(const short8*)(&FT[(jt * 16 + lr) * 40 + lg * 8]);
  f32x4 acco[4][2];
  #pragma unroll
  for (int it = 0; it < 4; ++it)
    #pragma unroll
    for (int jt = 0; jt < 2; ++jt) {
      f32x4 a = (f32x4){0.f, 0.f, 0.f, 0.f};
      acco[it][jt] = __builtin_amdgcn_mfma_f32_16x16x32_bf16(xf[it], ff[jt], a, 0, 0, 0);
    }
  #pragma unroll
  for (int it = 0; it < 4; ++it)
    #pragma unroll
    for (int jt = 0; jt < 2; ++jt)
      #pragma unroll
      for (int r = 0; r < 4; ++r) {
        int c = it * 16 + lg * 4 + r;
        int m = jt * 16 + lr;
        float v = (m < M) ? acco[it][jt][r] : 0.f;
        Xb[c * 40 + m] = __float2bfloat16(v);
      }

  // phase 5: vv[m] = cv + sum_c wv[c]*ot[c][m]  (lanes 0..M-1)
  if (l < M) {
    float s = cuv[1];
    #pragma unroll 8
    for (int c = 0; c < 64; ++c)
      s += wv[c] * __bfloat162float(Xb[c * 40 + l]);
    vv[l] = s;
  }

  // phase 6: att (lanes 0..24) -> AT[n*40+m]
  if (l < 25) {
    const int n = l;
    const float uu = uub[b * 1600 + t * 25 + n];
    float f[M];
    float mx = -1e30f;
    #pragma unroll
    for (int m = 0; m < M; ++m) {
      float v = uu + vv[m];
      v = v >= 0.f ? v : 0.2f * v;
      f[m] = v;
      mx = fmaxf(mx, v);
    }
    float sum = 0.f;
    #pragma unroll
    for (int m = 0; m < M; ++m) { f[m] = __expf(f[m] - mx); sum += f[m]; }
    float inv = 1.f / sum;
    #pragma unroll
    for (int m = 0; m < M; ++m)
      AT[n * 40 + m] = __float2bfloat16(f[m] * inv + Ck[n * M + m]);
  }

  // phase 7: Z = ot @ att^T (K=32): D[i=c][j=n] -> Zt (staged in dead Xb)
  short8 of[4], af[2];
  #pragma unroll
  for (int it = 0; it < 4; ++it)
    of[it] = *(const short8*)(&Xb[(it * 16 + lr) * 40 + lg * 8]);
  #pragma unroll
  for (int jt = 0; jt < 2; ++jt)
    af[jt] = *(const short8*)(&AT[(jt * 16 + lr) * 40 + lg * 8]);
  f32x4 accz[4][2];
  #pragma unroll
  for (int it = 0; it < 4; ++it)
    #pragma unroll
    for (int jt = 0; jt < 2; ++jt) {
      f32x4 a = (f32x4){0.f, 0.f, 0.f, 0.f};
      accz[it][jt] = __builtin_amdgcn_mfma_f32_16x16x32_bf16(of[it], af[jt], a, 0, 0, 0);
    }
  __hip_bfloat16* Zt = Xb;   // Xb dead after `of` reads (accz depends on of)
  #pragma unroll
  for (int it = 0; it < 4; ++it)
    #pragma unroll
    for (int jt = 0; jt < 2; ++jt)
      #pragma unroll
      for (int r = 0; r < 4; ++r) {
        int c = it * 16 + lg * 4 + r;
        int n = jt * 16 + lr;
        if (n < 25) Zt[n * 66 + c] = __float2bfloat16(accz[it][jt][r]);
      }

  // phase 8: coalesced ZH write (lane = c, 128B per row)
  for (int n = 0; n < 25; ++n)
    ZH[(size_t)(b * 1600 + t * 25 + n) * 128 + cioff + l] = Zt[n * 66 + l];
}

// ---- merged restore: blocks 0..1023 = branch 2 (M=19), 1024..2047 = branch 3 (M=15)
__global__ __launch_bounds__(256, 3) void restore_both(
    const __hip_bfloat16* __restrict__ HbTA,
    const float* __restrict__ F19, const float* __restrict__ F15,
    const float* __restrict__ A2, const float* __restrict__ A3,
    const float* __restrict__ ubuf2, const float* __restrict__ ubuf3,
    const float* __restrict__ uv,
    const float* __restrict__ Ck2, const float* __restrict__ Ck3,
    __hip_bfloat16* __restrict__ ZH) {
  __shared__ __hip_bfloat16 XbS[4][64 * 40];
  __shared__ __hip_bfloat16 FBS[4][32 * 40];   // scf overlays this
  __shared__ __hip_bfloat16 FTS[4][32 * 40];
  __shared__ __hip_bfloat16 ATS[4][32 * 40];
  __shared__ float vvS[4][32];
  const int w = threadIdx.x >> 6;
  if (blockIdx.x < 1024) {
    restore_body<19>(blockIdx.x, HbTA, F19, A2, ubuf2, uv + 64, uv + 256, Ck2,
                     ZH, 0, XbS[w], FBS[w], FTS[w], ATS[w], vvS[w]);
  } else {
    restore_body<15>(blockIdx.x - 1024, HbTA, F15, A3, ubuf3, uv + 192, uv + 258, Ck3,
                     ZH, 64, XbS[w], FBS[w], FTS[w], ATS[w], vvS[w]);
  }
}

// ---- restore GEMM via MFMA, wave-private 32-col slices, IN PLACE, no LDS/barriers.
__global__ __launch_bounds__(256) void restore_gemm_mfma(
    __hip_bfloat16* __restrict__ ZH, const __hip_bfloat16* __restrict__ WgT,
    const float* __restrict__ bg2, const float* __restrict__ bg3,
    const float* __restrict__ sconst) {
  const int tid = threadIdx.x;
  const int wv = tid >> 6, l = tid & 63;
  const int lr = l & 15, lg = l >> 4;
  const size_t col0 = ((size_t)blockIdx.x * 4 + wv) * 32;
  const ushort* Zg = (const ushort*)ZH;
  const ushort* Wu = (const ushort*)WgT;

  short8 afr[2][2][2];
  #pragma unroll
  for (int mt = 0; mt < 2; ++mt)
    #pragma unroll
    for (int br = 0; br < 2; ++br)
      #pragma unroll
      for (int ks = 0; ks < 2; ++ks)
        afr[mt][br][ks] = *(const short8*)(
            Zg + (col0 + mt * 16 + lr) * 128 + br * 64 + ks * 32 + lg * 8);

  f32x4 acc[2][8];
  #pragma unroll
  for (int nt = 0; nt < 8; ++nt) {
    const int br = nt >> 2;
    const int g = nt * 16 + lr;
    short8 b0 = *(const short8*)(Wu + g * 64 + lg * 8);
    short8 b1 = *(const short8*)(Wu + g * 64 + 32 + lg * 8);
    #pragma unroll
    for (int mt = 0; mt < 2; ++mt) {
      f32x4 a = (f32x4){0.f, 0.f, 0.f, 0.f};
      a = __builtin_amdgcn_mfma_f32_16x16x32_bf16(afr[mt][br][0], b0, a, 0, 0, 0);
      a = __builtin_amdgcn_mfma_f32_16x16x32_bf16(afr[mt][br][1], b1, a, 0, 0, 0);
      acc[mt][nt] = a;
    }
  }

  #pragma unroll
  for (int mt = 0; mt < 2; ++mt)
    #pragma unroll
    for (int r = 0; r < 4; ++r) {
      const size_t col = col0 + mt * 16 + lg * 4 + r;
      const int n = (int)(col % 25);
      const float s2v = sconst[n], s3v = sconst[25 + n];
      ushort* zp = (ushort*)ZH + col * 128;
      #pragma unroll
      for (int nt = 0; nt < 8; ++nt) {
        const int g = nt * 16 + lr;
        const float bo = (nt < 4) ? bg2[g] : bg3[g - 64];
        const float s = (nt < 4) ? s2v : s3v;
        float v = fmaxf((acc[mt][nt][r] + bo * s) * BN_SCALE_F, 0.f);
        __hip_bfloat16 h = __float2bfloat16(v);
        zp[g] = *(ushort*)&h;
      }
    }
}

// ---- final conv via MFMA, 8 waves/block (512 thr): wave = 80 cols x 32 o.
__global__ __launch_bounds__(512) void conv_mfma(
    const __hip_bfloat16* __restrict__ HbTA, const __hip_bfloat16* __restrict__ HbTB,
    const __hip_bfloat16* __restrict__ Wb, const float* __restrict__ x,
    const float* __restrict__ btcn, const float* __restrict__ aout_,
    float* __restrict__ out) {
  const int b = blockIdx.x / 5;
  const int col0 = (blockIdx.x % 5) * 320;
  const int tid = threadIdx.x;
  const int wave = tid >> 6, l = tid & 63;
  const int wcol = wave & 3, who = wave >> 2;
  const int lr = l & 15, lg = l >> 4;

  __shared__ __hip_bfloat16 Hl[384 * 40];
  __shared__ __hip_bfloat16 Wl[3 * 64 * 40];

  f32x4 acc[5][2];
  #pragma unroll
  for (int mt = 0; mt < 5; ++mt)
    #pragma unroll
    for (int nt = 0; nt < 2; ++nt) acc[mt][nt] = (f32x4){0.f, 0.f, 0.f, 0.f};

  const int base_a = (wcol * 80 + lr + 7) * 40 + lg * 8;
  const int base_b = (who * 32 + lr) * 40 + lg * 8;

  for (int ch = 0; ch < 8; ++ch) {
    const __hip_bfloat16* Ht = (ch < 4) ? HbTA : HbTB;
    const int ci0 = (ch & 3) * 32;
    const int wci0 = ch * 32;
    __syncthreads();
    #pragma unroll
    for (int it = 0; it < 3; ++it) {
      int idx = it * 512 + tid;
      int colr = idx >> 2, seg = idx & 3;
      int gcol = col0 - 32 + colr;
      uint4 v = {0u, 0u, 0u, 0u};
      if (gcol >= 0 && gcol < 1600)
        v = *(const uint4*)(Ht + ((size_t)(b * 1600 + gcol) * 128 + ci0 + seg * 8));
      *(uint4*)(&Hl[colr * 40 + seg * 8]) = v;
    }
    for (int idx = tid; idx < 768; idx += 512) {
      int o = (idx >> 2) & 63, kt = idx >> 8, seg = idx & 3;
      uint4 v = *(const uint4*)(Wb + ((kt * 64 + o) * 256 + wci0 + seg * 8));
      *(uint4*)(&Wl[(kt * 64 + o) * 40 + seg * 8]) = v;
    }
    __syncthreads();
    #pragma unroll
    for (int kt = 0; kt < 3; ++kt) {
      short8 af[5], bf[2];
      const int ab = base_a + kt * 1000;
      const int bb = base_b + kt * 2560;
      #pragma unroll
      for (int mt = 0; mt < 5; ++mt) af[mt] = *(const short8*)(&Hl[ab + mt * 640]);
      #pragma unroll
      for (int nt = 0; nt < 2; ++nt) bf[nt] = *(const short8*)(&Wl[bb + nt * 640]);
      #pragma unroll
      for (int mt = 0; mt < 5; ++mt)
        #pragma unroll
        for (int nt = 0; nt < 2; ++nt)
          acc[mt][nt] = __builtin_amdgcn_mfma_f32_16x16x32_bf16(af[mt], bf[nt],
                                                                acc[mt][nt], 0, 0, 0);
    }
  }

  const float aout = aout_[0];
  const int colbase = col0 + wcol * 80 + lg * 4;
  #pragma unroll
  for (int nt = 0; nt < 2; ++nt) {
    const int o = who * 32 + nt * 16 + lr;
    const float bo = btcn[o];
    const float* xr = x + ((size_t)b * 64 + o) * 1600 + colbase;
    float* op = out + ((size_t)b * 64 + o) * 1600 + colbase;
    #pragma unroll
    for (int mt = 0; mt < 5; ++mt) {
      float4 xv = *(const float4*)(xr + mt * 16);
      f32x4 a4 = acc[mt][nt];
      float4 res;
      float v0 = (a4[0] + bo) * BN_SCALE_F + xv.x;
      float v1 = (a4[1] + bo) * BN_SCALE_F + xv.y;
      float v2 = (a4[2] + bo) * BN_SCALE_F + xv.z;
      float v3 = (a4[3] + bo) * BN_SCALE_F + xv.w;
      res.x = v0 >= 0.f ? v0 : aout * v0;
      res.y = v1 >= 0.f ? v1 : aout * v1;
      res.z = v2 >= 0.f ? v2 : aout * v2;
      res.w = v3 >= 0.f ? v3 : aout * v3;
      *(float4*)(op + mt * 16) = res;
    }
  }
}

extern "C" void kernel_launch(void* const* d_in, const int* in_sizes, int n_in,
                              void* d_out, int out_size, void* d_ws, size_t ws_size,
                              hipStream_t stream) {
  const float* x     = (const float*)d_in[0];
  const float* A1    = (const float*)d_in[1];
  const float* A2    = (const float*)d_in[2];
  const float* A3    = (const float*)d_in[3];
  const float* Wp1   = (const float*)d_in[4];
  const float* ap1   = (const float*)d_in[5];
  const float* Wp2   = (const float*)d_in[6];
  const float* ap2   = (const float*)d_in[7];
  const float* Wg2   = (const float*)d_in[8];
  const float* bg2   = (const float*)d_in[9];
  const float* Wt2   = (const float*)d_in[10];
  const float* bt2   = (const float*)d_in[11];
  const float* Wph2  = (const float*)d_in[12];
  const float* bph2  = (const float*)d_in[13];
  const float* wcat2 = (const float*)d_in[14];
  const float* Ck2   = (const float*)d_in[15];
  const float* Wg3   = (const float*)d_in[16];
  const float* bg3   = (const float*)d_in[17];
  const float* Wt3   = (const float*)d_in[18];
  const float* bt3   = (const float*)d_in[19];
  const float* Wph3  = (const float*)d_in[20];
  const float* bph3  = (const float*)d_in[21];
  const float* wcat3 = (const float*)d_in[22];
  const float* Ck3   = (const float*)d_in[23];
  const float* Wtcn  = (const float*)d_in[24];
  const float* btcn  = (const float*)d_in[25];
  const float* aout  = (const float*)d_in[26];
  float* out = (float*)d_out;
  float* ws  = (float*)d_ws;

  __hip_bfloat16* ZH   = (__hip_bfloat16*)(ws + 6553600);   // Pp2 bf16 earlier life
  __hip_bfloat16* HbTA = (__hip_bfloat16*)(ws + 13107200);
  float* logits = ws + 19660800;                            // 54,400 f32
  float* preb = ws + 24641536;
  float* F19  = ws + 29622272;
  float* F15  = ws + 29652672;
  float* uv   = ws + 29676672;
  __hip_bfloat16* Wb   = (__hip_bfloat16*)preb;             // 49,152 bf16
  __hip_bfloat16* WgT  = (__hip_bfloat16*)(preb + 24576);   // 8,192 bf16
  float* sconst        = preb + 28672;                      // 50 f
  float* ubuf2         = preb + 32768;                      // 102,400 f
  float* ubuf3         = preb + 139264;                     // 102,400 f

  prep_all<<<438, 256, 0, stream>>>(Wt2, bt2, Wph2, bph2, wcat2,
                                    Wt3, bt3, Wph3, bph3, wcat3,
                                    Ck2, Ck3, Wg2, Wg3, Wtcn,
                                    uv, sconst, WgT, Wb, logits);
  ldnet1_mfma<<<1024, 256, 0, stream>>>(x, A1, uv, ZH /*Pp2*/, HbTA, ubuf2, ubuf3);

  // both pools in one pass over Pp2 bf16; atomicAdd into logits
  pool_partial<<<4096, 256, 0, stream>>>(ZH, Wp1, Wp2, ap1, ap2, logits);
  pool_reduce<<<64, 256, 0, stream>>>(logits, F19, F15);

  // both restore branches in ONE launch (disjoint ZH halves; Pp2 dead after pools)
  restore_both<<<2048, 256, 0, stream>>>(HbTA, F19, F15, A2, A3,
                                         ubuf2, ubuf3, uv, Ck2, Ck3, ZH);

  // shared Wg GEMM via MFMA, in place: ZH rows become HbTB rows (xcd2|xcd3 bf16)
  restore_gemm_mfma<<<800, 256, 0, stream>>>(ZH, WgT, bg2, bg3, sconst);

  // final conv via MFMA + bias + BN + residual + PReLU (8-wave blocks)
  conv_mfma<<<320, 512, 0, stream>>>(HbTA, ZH, Wb, x, btcn, aout, out);
}

// Round 19
// 154.771 us; speedup vs baseline: 1.2049x; 1.2049x over previous
//
#include <hip/hip_runtime.h>
#include <hip/hip_bf16.h>
#include <math.h>

// ---------------------------------------------------------------------------
// LDSTNet forward. B=64, C=64, T=64, N=25, Ci=32. Pools: R1=19, R2=15.
// (Round-17 configuration: partials+reduce pool, merged restore, 8-wave conv.)
//
// Workspace layout (floats):
//   (free)  @ 0          : 6,553,600
//   R1      @ 6,553,600  : 6,553,600  Pp2 bf16 [b][t][1600] -> ZH/HbTB bf16 [col][128]
//   R2      @ 13,107,200 : 6,553,600  HbT_A bf16 [b][1600][128] (0..63=x, 64..127=out1)
//   x2buf   @ 19,660,800 : 4,980,736  partials (64x64x850)
//   preb    @ 24,641,536 : 4,980,736  Wb | WgT | sconst | ubuf2 | ubuf3
//   F19     @ 29,622,272 : 30,400
//   F15     @ 29,652,672 : 24,000
//   uvbuf   @ 29,676,672 : 320
// ---------------------------------------------------------------------------

#define BN_SCALE_F 0.9999950000374997f

typedef __attribute__((ext_vector_type(8))) short short8;
typedef __attribute__((ext_vector_type(4))) float f32x4;

// ---- merged prep: block 0 = uv/sconst; blocks 1..32 = WgT; blocks 33..224 = Wb
__global__ void prep_all(const float* __restrict__ Wt2, const float* __restrict__ bt2,
                         const float* __restrict__ Wph2, const float* __restrict__ bph2,
                         const float* __restrict__ wcat2,
                         const float* __restrict__ Wt3, const float* __restrict__ bt3,
                         const float* __restrict__ Wph3, const float* __restrict__ bph3,
                         const float* __restrict__ wcat3,
                         const float* __restrict__ Ck2, const float* __restrict__ Ck3,
                         const float* __restrict__ Wg2, const float* __restrict__ Wg3,
                         const float* __restrict__ Wtcn,
                         float* __restrict__ uv, float* __restrict__ sconst,
                         __hip_bfloat16* __restrict__ WgT,
                         __hip_bfloat16* __restrict__ Wb) {
  const int bid = blockIdx.x;
  const int tid = threadIdx.x;
  if (bid == 0) {
    int c = tid;
    if (c < 64) {
      float s1 = 0.f, s2 = 0.f, s3 = 0.f, s4 = 0.f;
      for (int i = 0; i < 32; ++i) {
        s1 += wcat2[i]      * Wt2[i * 64 + c];
        s2 += wcat2[32 + i] * Wph2[i * 64 + c];
        s3 += wcat3[i]      * Wt3[i * 64 + c];
        s4 += wcat3[32 + i] * Wph3[i * 64 + c];
      }
      uv[c] = s1; uv[64 + c] = s2; uv[128 + c] = s3; uv[192 + c] = s4;
    }
    if (c == 0) {
      float c1 = 0.f, c2 = 0.f, c3 = 0.f, c4 = 0.f;
      for (int i = 0; i < 32; ++i) {
        c1 += wcat2[i] * bt2[i];       c2 += wcat2[32 + i] * bph2[i];
        c3 += wcat3[i] * bt3[i];       c4 += wcat3[32 + i] * bph3[i];
      }
      uv[256] = c1; uv[257] = c2; uv[258] = c3; uv[259] = c4;
    }
    if (c >= 64 && c < 89) {
      int n = c - 64;
      float s2 = 1.f, s3 = 1.f;
      for (int m = 0; m < 19; ++m) s2 += Ck2[n * 19 + m];
      for (int m = 0; m < 15; ++m) s3 += Ck3[n * 15 + m];
      sconst[n] = s2; sconst[25 + n] = s3;
    }
  } else if (bid < 33) {
    int idx = (bid - 1) * 256 + tid;
    int g = idx >> 6, c = idx & 63;
    float v = (g < 64) ? Wg2[g * 64 + c] : Wg3[(g - 64) * 64 + c];
    WgT[idx] = __float2bfloat16(v);
  } else {
    int idx = (bid - 33) * 256 + tid;
    int ci = idx & 255;
    int rest = idx >> 8;
    int o = rest & 63, kt = rest >> 6;
    Wb[idx] = __float2bfloat16(Wtcn[(o * 256 + ci) * 3 + kt]);
  }
}

// ---- ldnet1 via MFMA: one wave per (b,t), 4 waves/block, NO BARRIERS.
__global__ __launch_bounds__(256, 4) void ldnet1_mfma(
    const float* __restrict__ x, const float* __restrict__ A,
    const float* __restrict__ uvg,
    __hip_bfloat16* __restrict__ Pp2,
    __hip_bfloat16* __restrict__ HbTA,
    float* __restrict__ ubuf2, float* __restrict__ ubuf3) {
  const int b = blockIdx.x >> 4;
  const int t0 = (blockIdx.x & 15) << 2;
  const int tid = threadIdx.x;
  const int w = tid >> 6;
  const int l = tid & 63;
  const int t = t0 + w;
  const int lr = l & 15, lg = l >> 4;

  __shared__ __hip_bfloat16 XbS[4][64 * 40];   // x-tile -> otb -> P; cols 25..39 zero
  __shared__ __hip_bfloat16 FTS[4][32 * 40];   // FT[m][n] = FA[n][m]
  __shared__ float scS[4][25 * 25];            // gram scores only
  __hip_bfloat16* Xb = XbS[w];
  __hip_bfloat16* FT = FTS[w];
  float* scf = scS[w];

  const float* xp = x + b * 102400 + t * 25;   // + c*1600 + n
  typedef union { short8 v; ushort u[8]; } frag_u;

  // phase 0: zero FT; stage x-tile bf16 into Xb cols 0..31 (25..31 = 0).
  {
    uint32_t* z2 = (uint32_t*)FT;
    for (int i = l; i < 640; i += 64) z2[i] = 0u;
  }
  for (int idx = l; idx < 2048; idx += 64) {
    int c = idx >> 5, n = idx & 31;
    float v = (n < 25) ? xp[c * 1600 + n] : 0.f;
    Xb[c * 40 + n] = __float2bfloat16(v);
  }

  // phase 0b: HbTA x-part from LDS (lane = c)
  for (int n = 0; n < 25; ++n)
    HbTA[(size_t)(b * 1600 + t * 25 + n) * 128 + l] = Xb[l * 40 + n];

  // phase 1: gram frags from LDS + 8 MFMA -> scores
  frag_u yf[2][2];
  #pragma unroll
  for (int it = 0; it < 2; ++it) {
    const int n = it * 16 + lr;
    #pragma unroll
    for (int ks = 0; ks < 2; ++ks)
      #pragma unroll
      for (int j = 0; j < 8; ++j)
        yf[it][ks].u[j] = *(const ushort*)&Xb[(ks * 32 + lg * 8 + j) * 40 + n];
  }
  f32x4 accg[2][2];
  #pragma unroll
  for (int it = 0; it < 2; ++it)
    #pragma unroll
    for (int jt = 0; jt < 2; ++jt) {
      f32x4 a = (f32x4){0.f, 0.f, 0.f, 0.f};
      a = __builtin_amdgcn_mfma_f32_16x16x32_bf16(yf[it][0].v, yf[jt][0].v, a, 0, 0, 0);
      a = __builtin_amdgcn_mfma_f32_16x16x32_bf16(yf[it][1].v, yf[jt][1].v, a, 0, 0, 0);
      accg[it][jt] = a;
    }
  #pragma unroll
  for (int it = 0; it < 2; ++it)
    #pragma unroll
    for (int jt = 0; jt < 2; ++jt)
      #pragma unroll
      for (int r = 0; r < 4; ++r) {
        int i = it * 16 + lg * 4 + r;
        int j = jt * 16 + lr;
        if (i < 25 && j < 25) scf[i * 25 + j] = accg[it][jt][r];
      }

  // phase 2: softmax rows (lanes 0..24) -> FT[m*40+n] = FA[n][m]
  if (l < 25) {
    const int n = l;
    float f[25];
    float mx = -1e30f;
    #pragma unroll
    for (int m = 0; m < 25; ++m) { f[m] = scf[n * 25 + m] * 0.125f; mx = fmaxf(mx, f[m]); }
    float sum = 0.f;
    #pragma unroll
    for (int m = 0; m < 25; ++m) { f[m] = __expf(f[m] - mx); sum += f[m]; }
    float inv = 1.f / sum;
    #pragma unroll
    for (int m = 0; m < 25; ++m) {
      float v = f[m] * inv + A[n * 25 + m];
      FT[m * 40 + n] = __float2bfloat16(v);
    }
  }

  // phase 3: Q = out1^T. A = FT rows m, B = X rows c (short8 from LDS).
  short8 fa_[2];
  fa_[0] = *(const short8*)(&FT[lr * 40 + lg * 8]);
  fa_[1] = *(const short8*)(&FT[(16 + lr) * 40 + lg * 8]);
  short8 xb2v[4];
  #pragma unroll
  for (int jt = 0; jt < 4; ++jt)
    xb2v[jt] = *(const short8*)(&Xb[(jt * 16 + lr) * 40 + lg * 8]);
  f32x4 q_[2][4];
  #pragma unroll
  for (int it = 0; it < 2; ++it)
    #pragma unroll
    for (int jt = 0; jt < 4; ++jt) {
      f32x4 a = (f32x4){0.f, 0.f, 0.f, 0.f};
      q_[it][jt] = __builtin_amdgcn_mfma_f32_16x16x32_bf16(fa_[it], xb2v[jt], a, 0, 0, 0);
    }
  #pragma unroll
  for (int it = 0; it < 2; ++it)
    #pragma unroll
    for (int jt = 0; jt < 4; ++jt)
      #pragma unroll
      for (int r = 0; r < 4; ++r) {
        int m = it * 16 + lg * 4 + r;
        int c = jt * 16 + lr;
        if (m < 25) {
          __hip_bfloat16 h = __float2bfloat16(q_[it][jt][r]);
          Xb[c * 40 + m] = h;
          HbTA[(size_t)(b * 1600 + t * 25 + m) * 128 + 64 + c] = h;
        }
      }

  // phase 4: uu2/uu3 from otb (lanes 0..24)
  if (l < 25) {
    float s2 = uvg[256], s3 = uvg[258];
    #pragma unroll 8
    for (int c = 0; c < 64; ++c) {
      float o = __bfloat162float(Xb[c * 40 + l]);
      s2 += uvg[c] * o;
      s3 += uvg[128 + c] * o;
    }
    ubuf2[b * 1600 + t * 25 + l] = s2;
    ubuf3[b * 1600 + t * 25 + l] = s3;
  }

  // phase 5: P = otb @ FA
  short8 ofr[4];
  #pragma unroll
  for (int it = 0; it < 4; ++it)
    ofr[it] = *(const short8*)(&Xb[(it * 16 + lr) * 40 + lg * 8]);
  f32x4 p_[4][2];
  #pragma unroll
  for (int it = 0; it < 4; ++it)
    #pragma unroll
    for (int jt = 0; jt < 2; ++jt) {
      f32x4 a = (f32x4){0.f, 0.f, 0.f, 0.f};
      p_[it][jt] = __builtin_amdgcn_mfma_f32_16x16x32_bf16(ofr[it], fa_[jt], a, 0, 0, 0);
    }
  #pragma unroll
  for (int it = 0; it < 4; ++it)
    #pragma unroll
    for (int jt = 0; jt < 2; ++jt)
      #pragma unroll
      for (int r = 0; r < 4; ++r) {
        int c = it * 16 + lg * 4 + r;
        int n = jt * 16 + lr;
        if (n < 25) Xb[c * 40 + n] = __float2bfloat16(p_[it][jt][r]);
      }

  // phase 6: Pp2 bf16 coalesced
  for (int idx = l; idx < 1600; idx += 64) {
    int c = idx / 25, n = idx - c * 25;
    Pp2[b * 102400 + t * 1600 + idx] = Xb[c * 40 + n];
  }
}

// ---- pool partials, block = (b, c-channel); Pp2 bf16 [b][t][1600]
__global__ void pool_partial(const __hip_bfloat16* __restrict__ Pp2,
                             const float* __restrict__ Wp1, const float* __restrict__ Wp2,
                             const float* __restrict__ ap1_, const float* __restrict__ ap2_,
                             float* __restrict__ partials) {
  const int b = blockIdx.x >> 6;
  const int c = blockIdx.x & 63;
  const int tid = threadIdx.x;
  const float a1 = ap1_[0], a2 = ap2_[0];
  __shared__ float pg1[1600];
  __shared__ float pg2[1600];
  __shared__ float wct[64][36];
  for (int idx = tid; idx < 1600; idx += 256) {
    int t = idx / 25, n = idx - t * 25;
    float v = __bfloat162float(Pp2[b * 102400 + t * 1600 + c * 25 + n]);
    pg1[idx] = v >= 0.f ? v : a1 * v;
    pg2[idx] = v >= 0.f ? v : a2 * v;
  }
  for (int idx = tid; idx < 19 * 64; idx += 256) {
    int kl = idx & 63, r = idx >> 6;
    wct[kl][r] = Wp1[r * 4096 + (c << 6) + kl];
  }
  for (int idx = tid; idx < 15 * 64; idx += 256) {
    int kl = idx & 63, r = idx >> 6;
    wct[kl][20 + r] = Wp2[r * 4096 + (c << 6) + kl];
  }
  __syncthreads();
  if (tid < 225) {
    const int j = tid / 9;
    const int g = tid - j * 9;
    const bool br1 = (g < 5);
    const int r0 = br1 ? g * 4 : 20 + (g - 5) * 4;
    const float* pgc = br1 ? pg1 : pg2;
    float acc0 = 0.f, acc1 = 0.f, acc2 = 0.f, acc3 = 0.f;
    #pragma unroll 4
    for (int kl = 0; kl < 64; ++kl) {
      int off = kl * 25 + j;
      float p = pgc[(off & 63) * 25 + (off >> 6)];
      const float4 wv = *(const float4*)&wct[kl][r0];
      acc0 += p * wv.x; acc1 += p * wv.y; acc2 += p * wv.z; acc3 += p * wv.w;
    }
    const int base = (b * 64 + c) * 850;
    if (br1) {
      const int m = base + j * 19 + r0;
      partials[m] = acc0; partials[m + 1] = acc1; partials[m + 2] = acc2;
      if (g != 4) partials[m + 3] = acc3;
    } else {
      const int m = base + 475 + j * 15 + (r0 - 20);
      partials[m] = acc0; partials[m + 1] = acc1; partials[m + 2] = acc2;
      if (g != 8) partials[m + 3] = acc3;
    }
  }
}

// ---- reduce partials over 64 channel-chunks + per-branch softmax
__global__ void pool_reduce(const float* __restrict__ partials,
                            float* __restrict__ F19, float* __restrict__ F15) {
  const int b = blockIdx.x;
  const int tid = threadIdx.x;
  __shared__ float lg[850];
  for (int m = tid; m < 850; m += 256) {
    float s = 0.f;
    for (int ch = 0; ch < 64; ++ch) s += partials[(b * 64 + ch) * 850 + m];
    lg[m] = s;
  }
  __syncthreads();
  if (tid < 25) {
    const float* row = lg + tid * 19;
    float mx = -1e30f;
    for (int r = 0; r < 19; ++r) mx = fmaxf(mx, row[r]);
    float sum = 0.f;
    for (int r = 0; r < 19; ++r) sum += __expf(row[r] - mx);
    float inv = 1.f / sum;
    for (int r = 0; r < 19; ++r)
      F19[(b * 25 + tid) * 19 + r] = __expf(row[r] - mx) * inv;
  } else if (tid >= 32 && tid < 57) {
    const int j = tid - 32;
    const float* row = lg + 475 + j * 15;
    float mx = -1e30f;
    for (int r = 0; r < 15; ++r) mx = fmaxf(mx, row[r]);
    float sum = 0.f;
    for (int r = 0; r < 15; ++r) sum += __expf(row[r] - mx);
    float inv = 1.f / sum;
    for (int r = 0; r < 15; ++r)
      F15[(b * 25 + j) * 15 + r] = __expf(row[r] - mx) * inv;
  }
}

// ---- fused x2 + ldnet + attention + Z body (one wave per (b,t), NO BARRIERS).
// scf overlays FB (FB's last read precedes first scf write; wave-private, in-order DS).
template<int M>
__device__ __forceinline__ void restore_body(
    int bid, const __hip_bfloat16* __restrict__ HbTA, const float* __restrict__ F3g,
    const float* __restrict__ A,
    const float* __restrict__ uub, const float* __restrict__ wv,
    const float* __restrict__ cuv, const float* __restrict__ Ck,
    __hip_bfloat16* __restrict__ ZH, int cioff,
    __hip_bfloat16* Xb, __hip_bfloat16* FB, __hip_bfloat16* FT,
    __hip_bfloat16* AT, float* vv) {
  const int b = bid >> 4;
  const int t0 = (bid & 15) << 2;
  const int tid = threadIdx.x;
  const int w = tid >> 6;
  const int l = tid & 63;
  const int t = t0 + w;
  const int lr = l & 15, lg = l >> 4;
  float* scf = (float*)FB;   // overlay: FB read (phase 1 regs) precedes scf write (phase 2)

  typedef union { short8 v; ushort u[8]; } frag_u;
  const ushort* Hu = (const ushort*)HbTA;

  // phase 0: zero FB/FT/AT (B-operand pads must be 0)
  {
    uint32_t* z1 = (uint32_t*)FB;
    uint32_t* z2 = (uint32_t*)FT;
    uint32_t* z3 = (uint32_t*)AT;
    for (int i = l; i < 640; i += 64) { z1[i] = 0u; z2[i] = 0u; z3[i] = 0u; }
  }
  // phase 0a: FB[r*40+n] = bf16(F3[b][n][r])
  for (int idx = l; idx < M * 25; idx += 64) {
    int r = idx / 25, n = idx - r * 25;
    FB[r * 40 + n] = __float2bfloat16(F3g[(b * 25 + n) * M + r]);
  }

  // phase 1: X2 = out1 @ F3. A-frags from global HbTA (gated), B from FB.
  frag_u af0[4];
  #pragma unroll
  for (int it = 0; it < 4; ++it) {
    const int c = it * 16 + lr;
    #pragma unroll
    for (int jj = 0; jj < 8; ++jj) {
      int n = lg * 8 + jj;
      af0[it].u[jj] = (n < 25)
          ? Hu[(size_t)(b * 1600 + t * 25 + n) * 128 + 64 + c] : (ushort)0;
    }
  }
  short8 bf0[2];
  bf0[0] = *(const short8*)(&FB[lr * 40 + lg * 8]);
  bf0[1] = *(const short8*)(&FB[(16 + lr) * 40 + lg * 8]);
  f32x4 x2a[4][2];
  #pragma unroll
  for (int it = 0; it < 4; ++it)
    #pragma unroll
    for (int jt = 0; jt < 2; ++jt) {
      f32x4 a = (f32x4){0.f, 0.f, 0.f, 0.f};
      x2a[it][jt] = __builtin_amdgcn_mfma_f32_16x16x32_bf16(af0[it].v, bf0[jt], a, 0, 0, 0);
    }
  #pragma unroll
  for (int it = 0; it < 4; ++it)
    #pragma unroll
    for (int jt = 0; jt < 2; ++jt)
      #pragma unroll
      for (int rr = 0; rr < 4; ++rr) {
        int c = it * 16 + lg * 4 + rr;
        int r = jt * 16 + lr;
        float v = (r < M) ? x2a[it][jt][rr] : 0.f;
        Xb[c * 40 + r] = __float2bfloat16(v);
      }

  // phase 2: gram(X2) frags from LDS + 8 MFMA -> scores scf[i*26+j]
  frag_u yf[2][2];
  #pragma unroll
  for (int it = 0; it < 2; ++it) {
    const int n = it * 16 + lr;
    #pragma unroll
    for (int ks = 0; ks < 2; ++ks)
      #pragma unroll
      for (int j = 0; j < 8; ++j)
        yf[it][ks].u[j] = *(const ushort*)&Xb[(ks * 32 + lg * 8 + j) * 40 + n];
  }
  f32x4 accg[2][2];
  #pragma unroll
  for (int it = 0; it < 2; ++it)
    #pragma unroll
    for (int jt = 0; jt < 2; ++jt) {
      f32x4 a = (f32x4){0.f, 0.f, 0.f, 0.f};
      a = __builtin_amdgcn_mfma_f32_16x16x32_bf16(yf[it][0].v, yf[jt][0].v, a, 0, 0, 0);
      a = __builtin_amdgcn_mfma_f32_16x16x32_bf16(yf[it][1].v, yf[jt][1].v, a, 0, 0, 0);
      accg[it][jt] = a;
    }
  #pragma unroll
  for (int it = 0; it < 2; ++it)
    #pragma unroll
    for (int jt = 0; jt < 2; ++jt)
      #pragma unroll
      for (int r = 0; r < 4; ++r) {
        int i = it * 16 + lg * 4 + r;
        int j = jt * 16 + lr;
        if (i < M && j < M) scf[i * 26 + j] = accg[it][jt][r];
      }

  // phase 3: softmax rows (lanes 0..M-1) -> FT[m*40+n]
  if (l < M) {
    const int n = l;
    float f[M];
    float mx = -1e30f;
    #pragma unroll
    for (int m = 0; m < M; ++m) { f[m] = scf[n * 26 + m] * 0.125f; mx = fmaxf(mx, f[m]); }
    float sum = 0.f;
    #pragma unroll
    for (int m = 0; m < M; ++m) { f[m] = __expf(f[m] - mx); sum += f[m]; }
    float inv = 1.f / sum;
    #pragma unroll
    for (int m = 0; m < M; ++m) {
      float v = f[m] * inv + A[n * M + m];
      FT[m * 40 + n] = __float2bfloat16(v);
    }
  }

  // phase 4: ot = X2 @ FA (K=32), scatter into Xb (cols >= M -> 0)
  short8 xf[4], ff[2];
  #pragma unroll
  for (int it = 0; it < 4; ++it)
    xf[it] = *(const short8*)(&Xb[(it * 16 + lr) * 40 + lg * 8]);
  #pragma unroll
  for (int jt = 0; jt < 2; ++jt)
    ff[jt] = *(const short8*)(&FT[(jt * 16 + lr) * 40 + lg * 8]);
  f32x4 acco[4][2];
  #pragma unroll
  for (int it = 0; it < 4; ++it)
    #pragma unroll
    for (int jt = 0; jt < 2; ++jt) {
      f32x4 a = (f32x4){0.f, 0.f, 0.f, 0.f};
      acco[it][jt] = __builtin_amdgcn_mfma_f32_16x16x32_bf16(xf[it], ff[jt], a, 0, 0, 0);
    }
  #pragma unroll
  for (int it = 0; it < 4; ++it)
    #pragma unroll
    for (int jt = 0; jt < 2; ++jt)
      #pragma unroll
      for (int r = 0; r < 4; ++r) {
        int c = it * 16 + lg * 4 + r;
        int m = jt * 16 + lr;
        float v = (m < M) ? acco[it][jt][r] : 0.f;
        Xb[c * 40 + m] = __float2bfloat16(v);
      }

  // phase 5: vv[m] = cv + sum_c wv[c]*ot[c][m]  (lanes 0..M-1)
  if (l < M) {
    float s = cuv[1];
    #pragma unroll 8
    for (int c = 0; c < 64; ++c)
      s += wv[c] * __bfloat162float(Xb[c * 40 + l]);
    vv[l] = s;
  }

  // phase 6: att (lanes 0..24) -> AT[n*40+m]
  if (l < 25) {
    const int n = l;
    const float uu = uub[b * 1600 + t * 25 + n];
    float f[M];
    float mx = -1e30f;
    #pragma unroll
    for (int m = 0; m < M; ++m) {
      float v = uu + vv[m];
      v = v >= 0.f ? v : 0.2f * v;
      f[m] = v;
      mx = fmaxf(mx, v);
    }
    float sum = 0.f;
    #pragma unroll
    for (int m = 0; m < M; ++m) { f[m] = __expf(f[m] - mx); sum += f[m]; }
    float inv = 1.f / sum;
    #pragma unroll
    for (int m = 0; m < M; ++m)
      AT[n * 40 + m] = __float2bfloat16(f[m] * inv + Ck[n * M + m]);
  }

  // phase 7: Z = ot @ att^T (K=32): D[i=c][j=n] -> Zt (staged in dead Xb)
  short8 of[4], af[2];
  #pragma unroll
  for (int it = 0; it < 4; ++it)
    of[it] = *(const short8*)(&Xb[(it * 16 + lr) * 40 + lg * 8]);
  #pragma unroll
  for (int jt = 0; jt < 2; ++jt)
    af[jt] = *(const short8*)(&AT[(jt * 16 + lr) * 40 + lg * 8]);
  f32x4 accz[4][2];
  #pragma unroll
  for (int it = 0; it < 4; ++it)
    #pragma unroll
    for (int jt = 0; jt < 2; ++jt) {
      f32x4 a = (f32x4){0.f, 0.f, 0.f, 0.f};
      accz[it][jt] = __builtin_amdgcn_mfma_f32_16x16x32_bf16(of[it], af[jt], a, 0, 0, 0);
    }
  __hip_bfloat16* Zt = Xb;   // Xb dead after `of` reads (accz depends on of)
  #pragma unroll
  for (int it = 0; it < 4; ++it)
    #pragma unroll
    for (int jt = 0; jt < 2; ++jt)
      #pragma unroll
      for (int r = 0; r < 4; ++r) {
        int c = it * 16 + lg * 4 + r;
        int n = jt * 16 + lr;
        if (n < 25) Zt[n * 66 + c] = __float2bfloat16(accz[it][jt][r]);
      }

  // phase 8: coalesced ZH write (lane = c, 128B per row)
  for (int n = 0; n < 25; ++n)
    ZH[(size_t)(b * 1600 + t * 25 + n) * 128 + cioff + l] = Zt[n * 66 + l];
}

// ---- merged restore: blocks 0..1023 = branch 2 (M=19), 1024..2047 = branch 3 (M=15)
__global__ __launch_bounds__(256, 3) void restore_both(
    const __hip_bfloat16* __restrict__ HbTA,
    const float* __restrict__ F19, const float* __restrict__ F15,
    const float* __restrict__ A2, const float* __restrict__ A3,
    const float* __restrict__ ubuf2, const float* __restrict__ ubuf3,
    const float* __restrict__ uv,
    const float* __restrict__ Ck2, const float* __restrict__ Ck3,
    __hip_bfloat16* __restrict__ ZH) {
  __shared__ __hip_bfloat16 XbS[4][64 * 40];
  __shared__ __hip_bfloat16 FBS[4][32 * 40];   // scf overlays this
  __shared__ __hip_bfloat16 FTS[4][32 * 40];
  __shared__ __hip_bfloat16 ATS[4][32 * 40];
  __shared__ float vvS[4][32];
  const int w = threadIdx.x >> 6;
  if (blockIdx.x < 1024) {
    restore_body<19>(blockIdx.x, HbTA, F19, A2, ubuf2, uv + 64, uv + 256, Ck2,
                     ZH, 0, XbS[w], FBS[w], FTS[w], ATS[w], vvS[w]);
  } else {
    restore_body<15>(blockIdx.x - 1024, HbTA, F15, A3, ubuf3, uv + 192, uv + 258, Ck3,
                     ZH, 64, XbS[w], FBS[w], FTS[w], ATS[w], vvS[w]);
  }
}

// ---- restore GEMM via MFMA, wave-private 32-col slices, IN PLACE, no LDS/barriers.
__global__ __launch_bounds__(256) void restore_gemm_mfma(
    __hip_bfloat16* __restrict__ ZH, const __hip_bfloat16* __restrict__ WgT,
    const float* __restrict__ bg2, const float* __restrict__ bg3,
    const float* __restrict__ sconst) {
  const int tid = threadIdx.x;
  const int wv = tid >> 6, l = tid & 63;
  const int lr = l & 15, lg = l >> 4;
  const size_t col0 = ((size_t)blockIdx.x * 4 + wv) * 32;
  const ushort* Zg = (const ushort*)ZH;
  const ushort* Wu = (const ushort*)WgT;

  short8 afr[2][2][2];
  #pragma unroll
  for (int mt = 0; mt < 2; ++mt)
    #pragma unroll
    for (int br = 0; br < 2; ++br)
      #pragma unroll
      for (int ks = 0; ks < 2; ++ks)
        afr[mt][br][ks] = *(const short8*)(
            Zg + (col0 + mt * 16 + lr) * 128 + br * 64 + ks * 32 + lg * 8);

  f32x4 acc[2][8];
  #pragma unroll
  for (int nt = 0; nt < 8; ++nt) {
    const int br = nt >> 2;
    const int g = nt * 16 + lr;
    short8 b0 = *(const short8*)(Wu + g * 64 + lg * 8);
    short8 b1 = *(const short8*)(Wu + g * 64 + 32 + lg * 8);
    #pragma unroll
    for (int mt = 0; mt < 2; ++mt) {
      f32x4 a = (f32x4){0.f, 0.f, 0.f, 0.f};
      a = __builtin_amdgcn_mfma_f32_16x16x32_bf16(afr[mt][br][0], b0, a, 0, 0, 0);
      a = __builtin_amdgcn_mfma_f32_16x16x32_bf16(afr[mt][br][1], b1, a, 0, 0, 0);
      acc[mt][nt] = a;
    }
  }

  #pragma unroll
  for (int mt = 0; mt < 2; ++mt)
    #pragma unroll
    for (int r = 0; r < 4; ++r) {
      const size_t col = col0 + mt * 16 + lg * 4 + r;
      const int n = (int)(col % 25);
      const float s2v = sconst[n], s3v = sconst[25 + n];
      ushort* zp = (ushort*)ZH + col * 128;
      #pragma unroll
      for (int nt = 0; nt < 8; ++nt) {
        const int g = nt * 16 + lr;
        const float bo = (nt < 4) ? bg2[g] : bg3[g - 64];
        const float s = (nt < 4) ? s2v : s3v;
        float v = fmaxf((acc[mt][nt][r] + bo * s) * BN_SCALE_F, 0.f);
        __hip_bfloat16 h = __float2bfloat16(v);
        zp[g] = *(ushort*)&h;
      }
    }
}

// ---- final conv via MFMA, 8 waves/block (512 thr): wave = 80 cols x 32 o.
__global__ __launch_bounds__(512) void conv_mfma(
    const __hip_bfloat16* __restrict__ HbTA, const __hip_bfloat16* __restrict__ HbTB,
    const __hip_bfloat16* __restrict__ Wb, const float* __restrict__ x,
    const float* __restrict__ btcn, const float* __restrict__ aout_,
    float* __restrict__ out) {
  const int b = blockIdx.x / 5;
  const int col0 = (blockIdx.x % 5) * 320;
  const int tid = threadIdx.x;
  const int wave = tid >> 6, l = tid & 63;
  const int wcol = wave & 3, who = wave >> 2;
  const int lr = l & 15, lg = l >> 4;

  __shared__ __hip_bfloat16 Hl[384 * 40];
  __shared__ __hip_bfloat16 Wl[3 * 64 * 40];

  f32x4 acc[5][2];
  #pragma unroll
  for (int mt = 0; mt < 5; ++mt)
    #pragma unroll
    for (int nt = 0; nt < 2; ++nt) acc[mt][nt] = (f32x4){0.f, 0.f, 0.f, 0.f};

  const int base_a = (wcol * 80 + lr + 7) * 40 + lg * 8;
  const int base_b = (who * 32 + lr) * 40 + lg * 8;

  for (int ch = 0; ch < 8; ++ch) {
    const __hip_bfloat16* Ht = (ch < 4) ? HbTA : HbTB;
    const int ci0 = (ch & 3) * 32;
    const int wci0 = ch * 32;
    __syncthreads();
    #pragma unroll
    for (int it = 0; it < 3; ++it) {
      int idx = it * 512 + tid;
      int colr = idx >> 2, seg = idx & 3;
      int gcol = col0 - 32 + colr;
      uint4 v = {0u, 0u, 0u, 0u};
      if (gcol >= 0 && gcol < 1600)
        v = *(const uint4*)(Ht + ((size_t)(b * 1600 + gcol) * 128 + ci0 + seg * 8));
      *(uint4*)(&Hl[colr * 40 + seg * 8]) = v;
    }
    for (int idx = tid; idx < 768; idx += 512) {
      int o = (idx >> 2) & 63, kt = idx >> 8, seg = idx & 3;
      uint4 v = *(const uint4*)(Wb + ((kt * 64 + o) * 256 + wci0 + seg * 8));
      *(uint4*)(&Wl[(kt * 64 + o) * 40 + seg * 8]) = v;
    }
    __syncthreads();
    #pragma unroll
    for (int kt = 0; kt < 3; ++kt) {
      short8 af[5], bf[2];
      const int ab = base_a + kt * 1000;
      const int bb = base_b + kt * 2560;
      #pragma unroll
      for (int mt = 0; mt < 5; ++mt) af[mt] = *(const short8*)(&Hl[ab + mt * 640]);
      #pragma unroll
      for (int nt = 0; nt < 2; ++nt) bf[nt] = *(const short8*)(&Wl[bb + nt * 640]);
      #pragma unroll
      for (int mt = 0; mt < 5; ++mt)
        #pragma unroll
        for (int nt = 0; nt < 2; ++nt)
          acc[mt][nt] = __builtin_amdgcn_mfma_f32_16x16x32_bf16(af[mt], bf[nt],
                                                                acc[mt][nt], 0, 0, 0);
    }
  }

  const float aout = aout_[0];
  const int colbase = col0 + wcol * 80 + lg * 4;
  #pragma unroll
  for (int nt = 0; nt < 2; ++nt) {
    const int o = who * 32 + nt * 16 + lr;
    const float bo = btcn[o];
    const float* xr = x + ((size_t)b * 64 + o) * 1600 + colbase;
    float* op = out + ((size_t)b * 64 + o) * 1600 + colbase;
    #pragma unroll
    for (int mt = 0; mt < 5; ++mt) {
      float4 xv = *(const float4*)(xr + mt * 16);
      f32x4 a4 = acc[mt][nt];
      float4 res;
      float v0 = (a4[0] + bo) * BN_SCALE_F + xv.x;
      float v1 = (a4[1] + bo) * BN_SCALE_F + xv.y;
      float v2 = (a4[2] + bo) * BN_SCALE_F + xv.z;
      float v3 = (a4[3] + bo) * BN_SCALE_F + xv.w;
      res.x = v0 >= 0.f ? v0 : aout * v0;
      res.y = v1 >= 0.f ? v1 : aout * v1;
      res.z = v2 >= 0.f ? v2 : aout * v2;
      res.w = v3 >= 0.f ? v3 : aout * v3;
      *(float4*)(op + mt * 16) = res;
    }
  }
}

extern "C" void kernel_launch(void* const* d_in, const int* in_sizes, int n_in,
                              void* d_out, int out_size, void* d_ws, size_t ws_size,
                              hipStream_t stream) {
  const float* x     = (const float*)d_in[0];
  const float* A1    = (const float*)d_in[1];
  const float* A2    = (const float*)d_in[2];
  const float* A3    = (const float*)d_in[3];
  const float* Wp1   = (const float*)d_in[4];
  const float* ap1   = (const float*)d_in[5];
  const float* Wp2   = (const float*)d_in[6];
  const float* ap2   = (const float*)d_in[7];
  const float* Wg2   = (const float*)d_in[8];
  const float* bg2   = (const float*)d_in[9];
  const float* Wt2   = (const float*)d_in[10];
  const float* bt2   = (const float*)d_in[11];
  const float* Wph2  = (const float*)d_in[12];
  const float* bph2  = (const float*)d_in[13];
  const float* wcat2 = (const float*)d_in[14];
  const float* Ck2   = (const float*)d_in[15];
  const float* Wg3   = (const float*)d_in[16];
  const float* bg3   = (const float*)d_in[17];
  const float* Wt3   = (const float*)d_in[18];
  const float* bt3   = (const float*)d_in[19];
  const float* Wph3  = (const float*)d_in[20];
  const float* bph3  = (const float*)d_in[21];
  const float* wcat3 = (const float*)d_in[22];
  const float* Ck3   = (const float*)d_in[23];
  const float* Wtcn  = (const float*)d_in[24];
  const float* btcn  = (const float*)d_in[25];
  const float* aout  = (const float*)d_in[26];
  float* out = (float*)d_out;
  float* ws  = (float*)d_ws;

  __hip_bfloat16* ZH   = (__hip_bfloat16*)(ws + 6553600);   // Pp2 bf16 earlier life
  __hip_bfloat16* HbTA = (__hip_bfloat16*)(ws + 13107200);
  float* x2b  = ws + 19660800;
  float* preb = ws + 24641536;
  float* F19  = ws + 29622272;
  float* F15  = ws + 29652672;
  float* uv   = ws + 29676672;
  float* partials = x2b;
  __hip_bfloat16* Wb   = (__hip_bfloat16*)preb;             // 49,152 bf16
  __hip_bfloat16* WgT  = (__hip_bfloat16*)(preb + 24576);   // 8,192 bf16
  float* sconst        = preb + 28672;                      // 50 f
  float* ubuf2         = preb + 32768;                      // 102,400 f
  float* ubuf3         = preb + 139264;                     // 102,400 f

  prep_all<<<225, 256, 0, stream>>>(Wt2, bt2, Wph2, bph2, wcat2,
                                    Wt3, bt3, Wph3, bph3, wcat3,
                                    Ck2, Ck3, Wg2, Wg3, Wtcn,
                                    uv, sconst, WgT, Wb);
  ldnet1_mfma<<<1024, 256, 0, stream>>>(x, A1, uv, ZH /*Pp2*/, HbTA, ubuf2, ubuf3);

  // both pools in one pass over Pp2 bf16 (block per (b, channel))
  pool_partial<<<4096, 256, 0, stream>>>(ZH, Wp1, Wp2, ap1, ap2, partials);
  pool_reduce<<<64, 256, 0, stream>>>(partials, F19, F15);

  // both restore branches in ONE launch (disjoint ZH halves; Pp2 dead after pools)
  restore_both<<<2048, 256, 0, stream>>>(HbTA, F19, F15, A2, A3,
                                         ubuf2, ubuf3, uv, Ck2, Ck3, ZH);

  // shared Wg GEMM via MFMA, in place: ZH rows become HbTB rows (xcd2|xcd3 bf16)
  restore_gemm_mfma<<<800, 256, 0, stream>>>(ZH, WgT, bg2, bg3, sconst);

  // final conv via MFMA + bias + BN + residual + PReLU (8-wave blocks)
  conv_mfma<<<320, 512, 0, stream>>>(HbTA, ZH, Wb, x, btcn, aout, out);
}